// Round 1
// baseline (13357.072 us; speedup 1.0000x reference)
//
#include <hip/hip_runtime.h>

// Problem constants (match reference setup_inputs / module hyperparams)
#define BATCH 4
#define HGT   720
#define WID   1280
#define HW    (HGT * WID)           // 921600
#define NPIX  (BATCH * HW)          // 3686400
#define INV2S2 0.22222222222222222f // 1/(2*1.5^2)
#define LAMBDA_E (30.0f / 255.0f)
#define INV_LAMBDA_E (255.0f / 30.0f)
#define THRESH 1e-6f
#define EPSV   1e-6f

// ---------------------------------------------------------------------------
// Kernel 1: photometric error = mean_c |i1 - warp(i2, flow)|   -> err [N]
// ---------------------------------------------------------------------------
__global__ __launch_bounds__(256) void err_kernel(
    const float* __restrict__ i1, const float* __restrict__ i2,
    const float* __restrict__ flow, float* __restrict__ err) {
  int n = blockIdx.x * blockDim.x + threadIdx.x;
  if (n >= NPIX) return;
  int b = n / HW;
  int r = n - b * HW;
  int y = r / WID;
  int x = r - y * WID;

  float u = flow[(b * 2 + 0) * HW + r];
  float v = flow[(b * 2 + 1) * HW + r];
  float gx = fminf(fmaxf((float)x + u, 0.0f), (float)(WID - 1));
  float gy = fminf(fmaxf((float)y + v, 0.0f), (float)(HGT - 1));
  float x0f = floorf(gx), y0f = floorf(gy);
  int x0 = (int)x0f, y0 = (int)y0f;
  int x1 = min(x0 + 1, WID - 1), y1 = min(y0 + 1, HGT - 1);
  float wx = gx - x0f, wy = gy - y0f;
  float w00 = (1.0f - wx) * (1.0f - wy);
  float w01 = wx * (1.0f - wy);
  float w10 = (1.0f - wx) * wy;
  float w11 = wx * wy;
  int i00 = y0 * WID + x0, i01 = y0 * WID + x1;
  int i10 = y1 * WID + x0, i11 = y1 * WID + x1;

  const float* i2b = i2 + (size_t)b * 3 * HW;
  const float* i1b = i1 + (size_t)b * 3 * HW;
  float s = 0.0f;
#pragma unroll
  for (int c = 0; c < 3; ++c) {
    const float* p = i2b + c * HW;
    float wv = p[i00] * w00 + p[i01] * w01 + p[i10] * w10 + p[i11] * w11;
    s += fabsf(i1b[c * HW + r] - wv);
  }
  err[n] = s * (1.0f / 3.0f);
}

// ---------------------------------------------------------------------------
// Kernel 2: 3x3 zero-padded box filter of err, then fw = exp(-(e/LE)^2)
// ---------------------------------------------------------------------------
__global__ __launch_bounds__(256) void fw_kernel(
    const float* __restrict__ err, float* __restrict__ fw) {
  int n = blockIdx.x * blockDim.x + threadIdx.x;
  if (n >= NPIX) return;
  int b = n / HW;
  int r = n - b * HW;
  int y = r / WID;
  int x = r - y * WID;
  const float* e = err + (size_t)b * HW;
  float s = 0.0f;
#pragma unroll
  for (int dy = -1; dy <= 1; ++dy) {
    int yy = y + dy;
    if (yy < 0 || yy >= HGT) continue;
#pragma unroll
    for (int dx = -1; dx <= 1; ++dx) {
      int xx = x + dx;
      if (xx < 0 || xx >= WID) continue;
      s += e[yy * WID + xx];
    }
  }
  s *= (1.0f / 9.0f);
  float t = s * INV_LAMBDA_E;
  fw[n] = expf(-t * t);   // LAMBDA_V == 1
}

// ---------------------------------------------------------------------------
// Kernel 3: forward gaussian splat (scatter with atomics).
// p: 3 planes of [N]; pw, rw: 1 plane each.
// Note: TAO_R truncation is provably dead (min g = exp(-8/4.5) = 0.169 > 0.05)
// so the 2-D gaussian separates into gx[4]*gy[4].
// ---------------------------------------------------------------------------
__global__ __launch_bounds__(256) void splat_kernel(
    const float* __restrict__ flow, const float* __restrict__ img,
    const float* __restrict__ fw, float* __restrict__ p,
    float* __restrict__ pw, float* __restrict__ rw) {
  int n = blockIdx.x * blockDim.x + threadIdx.x;
  if (n >= NPIX) return;
  int b = n / HW;
  int r = n - b * HW;
  int y = r / WID;
  int x = r - y * WID;

  float u = flow[(b * 2 + 0) * HW + r];
  float v = flow[(b * 2 + 1) * HW + r];
  float tx = (float)x + u;
  float ty = (float)y + v;
  float fx = floorf(tx), fy = floorf(ty);
  int ixb = (int)fx, iyb = (int)fy;
  float fracx = tx - fx, fracy = ty - fy;

  float gxv[4], gyv[4];
#pragma unroll
  for (int d = 0; d < 4; ++d) {
    float ddx = fracx - (float)(d - 1);
    gxv[d] = __expf(-ddx * ddx * INV2S2);
    float ddy = fracy - (float)(d - 1);
    gyv[d] = __expf(-ddy * ddy * INV2S2);
  }

  float fwv = fw[n];
  const float* ib = img + (size_t)b * 3 * HW;
  float s0 = ib[0 * HW + r] * fwv;
  float s1 = ib[1 * HW + r] * fwv;
  float s2 = ib[2 * HW + r] * fwv;

  int base = b * HW;
#pragma unroll
  for (int dy = 0; dy < 4; ++dy) {
    int iy = iyb + dy - 1;
    if (iy < 0 || iy >= HGT) continue;
    float gy = gyv[dy];
#pragma unroll
    for (int dx = 0; dx < 4; ++dx) {
      int ix = ixb + dx - 1;
      if (ix < 0 || ix >= WID) continue;
      float g = gxv[dx] * gy;
      int gi = base + iy * WID + ix;
      atomicAdd(p + gi, s0 * g);
      atomicAdd(p + NPIX + gi, s1 * g);
      atomicAdd(p + 2 * NPIX + gi, s2 * g);
      atomicAdd(pw + gi, fwv * g);
      atomicAdd(rw + gi, g);
    }
  }
}

// ---------------------------------------------------------------------------
// Kernel 4a: branch-1 accumulate: out = i1*w1 (write), den = w1 (write)
// ---------------------------------------------------------------------------
__global__ __launch_bounds__(256) void acc1_kernel(
    const float* __restrict__ p, const float* __restrict__ pw,
    const float* __restrict__ rw, float* __restrict__ out,
    float* __restrict__ den) {
  int n = blockIdx.x * blockDim.x + threadIdx.x;
  if (n >= NPIX) return;
  int b = n / HW;
  int r = n - b * HW;
  float pwv = pw[n], rwv = rw[n];
  float w = pwv / (rwv + THRESH);
  den[n] = w;
  float scale = w / (pwv + THRESH);  // == (1/(pw+T)) * w
  int ob = b * 3 * HW + r;
  out[ob + 0 * HW] = p[n] * scale;
  out[ob + 1 * HW] = p[NPIX + n] * scale;
  out[ob + 2 * HW] = p[2 * NPIX + n] * scale;
}

// ---------------------------------------------------------------------------
// Kernel 4b: branch-2 accumulate + final blend:
//   out = (out + i2*w2) / (den + w2 + EPS)
// ---------------------------------------------------------------------------
__global__ __launch_bounds__(256) void acc2_kernel(
    const float* __restrict__ p, const float* __restrict__ pw,
    const float* __restrict__ rw, const float* __restrict__ den,
    float* __restrict__ out) {
  int n = blockIdx.x * blockDim.x + threadIdx.x;
  if (n >= NPIX) return;
  int b = n / HW;
  int r = n - b * HW;
  float pwv = pw[n], rwv = rw[n];
  float w = pwv / (rwv + THRESH);
  float scale = w / (pwv + THRESH);
  float d = den[n] + w + EPSV;
  float invd = 1.0f / d;
  int ob = b * 3 * HW + r;
  out[ob + 0 * HW] = (out[ob + 0 * HW] + p[n] * scale) * invd;
  out[ob + 1 * HW] = (out[ob + 1 * HW] + p[NPIX + n] * scale) * invd;
  out[ob + 2 * HW] = (out[ob + 2 * HW] + p[2 * NPIX + n] * scale) * invd;
}

// ---------------------------------------------------------------------------
// Launcher. Workspace layout (floats):
//   [0, 3N)   p (3 planes); p[0] also aliases err scratch (err consumed
//             before the memset that zeroes p)
//   [3N, 4N)  pw
//   [4N, 5N)  rw
//   [5N, 6N)  fw
//   [6N, 7N)  den (w1)
// Total 7N floats = 103.2 MB.
// ---------------------------------------------------------------------------
extern "C" void kernel_launch(void* const* d_in, const int* in_sizes, int n_in,
                              void* d_out, int out_size, void* d_ws,
                              size_t ws_size, hipStream_t stream) {
  const float* input1 = (const float*)d_in[0];
  const float* input2 = (const float*)d_in[1];
  const float* flow3  = (const float*)d_in[2];
  const float* flow4  = (const float*)d_in[3];
  float* out = (float*)d_out;

  float* ws  = (float*)d_ws;
  float* p   = ws;                    // 3 planes; p[0] doubles as err scratch
  float* err = ws;
  float* pw  = ws + (size_t)3 * NPIX;
  float* rw  = ws + (size_t)4 * NPIX;
  float* fw  = ws + (size_t)5 * NPIX;
  float* den = ws + (size_t)6 * NPIX;

  const int threads = 256;
  const int blocks = (NPIX + threads - 1) / threads;

  // ---- branch 1: warp input2 by flow3, compare to input1, splat input1 ----
  err_kernel<<<blocks, threads, 0, stream>>>(input1, input2, flow3, err);
  fw_kernel<<<blocks, threads, 0, stream>>>(err, fw);
  hipMemsetAsync(ws, 0, (size_t)5 * NPIX * sizeof(float), stream);  // p,pw,rw
  splat_kernel<<<blocks, threads, 0, stream>>>(flow3, input1, fw, p, pw, rw);
  acc1_kernel<<<blocks, threads, 0, stream>>>(p, pw, rw, out, den);

  // ---- branch 2: warp input1 by flow4, compare to input2, splat input2 ----
  err_kernel<<<blocks, threads, 0, stream>>>(input2, input1, flow4, err);
  fw_kernel<<<blocks, threads, 0, stream>>>(err, fw);
  hipMemsetAsync(ws, 0, (size_t)5 * NPIX * sizeof(float), stream);
  splat_kernel<<<blocks, threads, 0, stream>>>(flow4, input2, fw, p, pw, rw);
  acc2_kernel<<<blocks, threads, 0, stream>>>(p, pw, rw, den, out);
}

// Round 2
// 3450.018 us; speedup vs baseline: 3.8716x; 3.8716x over previous
//
#include <hip/hip_runtime.h>

// Problem constants (match reference setup_inputs / module hyperparams)
#define BATCH 4
#define HGT   720
#define WID   1280
#define HW    (HGT * WID)           // 921600
#define NPIX  (BATCH * HW)          // 3686400
#define INV2S2 0.22222222222222222f // 1/(2*1.5^2)
#define INV_LAMBDA_E (255.0f / 30.0f)
#define THRESH 1e-6f
#define EPSV   1e-6f

// Splat tiling
#define TILE   32
#define MARGIN 6                    // P(|N(0,1)| > ~5) ~ 3e-7 -> fallback ~never
#define EXT    (TILE + 2 * MARGIN)  // 44
#define EXTC   (EXT * EXT)          // 1936 cells; 5 planes * 4B = 38720 B LDS

// ---------------------------------------------------------------------------
// Kernel 1: photometric error = mean_c |i1 - warp(i2, flow)|   -> err [N]
// ---------------------------------------------------------------------------
__global__ __launch_bounds__(256) void err_kernel(
    const float* __restrict__ i1, const float* __restrict__ i2,
    const float* __restrict__ flow, float* __restrict__ err) {
  int n = blockIdx.x * blockDim.x + threadIdx.x;
  if (n >= NPIX) return;
  int b = n / HW;
  int r = n - b * HW;
  int y = r / WID;
  int x = r - y * WID;

  float u = flow[(b * 2 + 0) * HW + r];
  float v = flow[(b * 2 + 1) * HW + r];
  float gx = fminf(fmaxf((float)x + u, 0.0f), (float)(WID - 1));
  float gy = fminf(fmaxf((float)y + v, 0.0f), (float)(HGT - 1));
  float x0f = floorf(gx), y0f = floorf(gy);
  int x0 = (int)x0f, y0 = (int)y0f;
  int x1 = min(x0 + 1, WID - 1), y1 = min(y0 + 1, HGT - 1);
  float wx = gx - x0f, wy = gy - y0f;
  float w00 = (1.0f - wx) * (1.0f - wy);
  float w01 = wx * (1.0f - wy);
  float w10 = (1.0f - wx) * wy;
  float w11 = wx * wy;
  int i00 = y0 * WID + x0, i01 = y0 * WID + x1;
  int i10 = y1 * WID + x0, i11 = y1 * WID + x1;

  const float* i2b = i2 + (size_t)b * 3 * HW;
  const float* i1b = i1 + (size_t)b * 3 * HW;
  float s = 0.0f;
#pragma unroll
  for (int c = 0; c < 3; ++c) {
    const float* p = i2b + c * HW;
    float wv = p[i00] * w00 + p[i01] * w01 + p[i10] * w10 + p[i11] * w11;
    s += fabsf(i1b[c * HW + r] - wv);
  }
  err[n] = s * (1.0f / 3.0f);
}

// ---------------------------------------------------------------------------
// Kernel 2: 3x3 zero-padded box filter of err, then fw = exp(-(e/LE)^2)
// ---------------------------------------------------------------------------
__global__ __launch_bounds__(256) void fw_kernel(
    const float* __restrict__ err, float* __restrict__ fw) {
  int n = blockIdx.x * blockDim.x + threadIdx.x;
  if (n >= NPIX) return;
  int b = n / HW;
  int r = n - b * HW;
  int y = r / WID;
  int x = r - y * WID;
  const float* e = err + (size_t)b * HW;
  float s = 0.0f;
#pragma unroll
  for (int dy = -1; dy <= 1; ++dy) {
    int yy = y + dy;
    if (yy < 0 || yy >= HGT) continue;
#pragma unroll
    for (int dx = -1; dx <= 1; ++dx) {
      int xx = x + dx;
      if (xx < 0 || xx >= WID) continue;
      s += e[yy * WID + xx];
    }
  }
  s *= (1.0f / 9.0f);
  float t = s * INV_LAMBDA_E;
  fw[n] = expf(-t * t);   // LAMBDA_V == 1
}

// ---------------------------------------------------------------------------
// Kernel 3: tiled forward gaussian splat.
// Each block owns a 32x32 source tile; accumulates its 16-tap splats into a
// 44x44 extended LDS tile (5 planes) with LDS atomics, then flushes nonzero
// cells with one global atomic per plane. Pixels whose tap window exits the
// extended tile (P ~ 1e-6) fall back to direct global atomics.
// Image-bounds masking of the reference is realized by not flushing cells
// whose global coords are outside the image.
// TAO_R truncation is provably dead (min g = exp(-8/4.5) = 0.169 > 0.05).
// ---------------------------------------------------------------------------
__global__ __launch_bounds__(256) void splat_tiled_kernel(
    const float* __restrict__ flow, const float* __restrict__ img,
    const float* __restrict__ fw, float* __restrict__ p,
    float* __restrict__ pw, float* __restrict__ rw) {
  __shared__ float sm[5 * EXTC];
  for (int i = threadIdx.x; i < 5 * EXTC; i += 256) sm[i] = 0.0f;
  __syncthreads();

  const int b = blockIdx.z;
  const int tx0 = blockIdx.x * TILE;
  const int ty0 = blockIdx.y * TILE;
  const int ex0 = tx0 - MARGIN;
  const int ey0 = ty0 - MARGIN;
  const float* fu  = flow + (size_t)(b * 2 + 0) * HW;
  const float* fv  = flow + (size_t)(b * 2 + 1) * HW;
  const float* ib  = img + (size_t)b * 3 * HW;
  const float* fwb = fw + (size_t)b * HW;

  const int lx  = threadIdx.x & 31;
  const int lr0 = threadIdx.x >> 5;
  const int x = tx0 + lx;   // always < WID (1280 % 32 == 0)

#pragma unroll
  for (int k = 0; k < 4; ++k) {
    int y = ty0 + lr0 + k * 8;
    if (y >= HGT) continue;          // bottom tile row is partial (720 = 22.5*32)
    int r = y * WID + x;
    float u = fu[r], v = fv[r];
    float txf = (float)x + u, tyf = (float)y + v;
    float fx = floorf(txf), fy = floorf(tyf);
    int ixb = (int)fx, iyb = (int)fy;
    float fracx = txf - fx, fracy = tyf - fy;

    float gxv[4], gyv[4];
#pragma unroll
    for (int d = 0; d < 4; ++d) {
      float ddx = fracx - (float)(d - 1);
      gxv[d] = __expf(-ddx * ddx * INV2S2);
      float ddy = fracy - (float)(d - 1);
      gyv[d] = __expf(-ddy * ddy * INV2S2);
    }

    float fwv = fwb[r];
    float s0 = ib[0 * HW + r] * fwv;
    float s1 = ib[1 * HW + r] * fwv;
    float s2 = ib[2 * HW + r] * fwv;

    int lix = ixb - ex0, liy = iyb - ey0;
    if (lix >= 1 && lix <= EXT - 3 && liy >= 1 && liy <= EXT - 3) {
      // in-tile fast path: 16 taps, no bounds checks (flush masks OOB cells)
#pragma unroll
      for (int dy = 0; dy < 4; ++dy) {
        float gy = gyv[dy];
        int rowb = (liy + dy - 1) * EXT + (lix - 1);
#pragma unroll
        for (int dx = 0; dx < 4; ++dx) {
          float g = gxv[dx] * gy;
          int cell = rowb + dx;
          unsafeAtomicAdd(&sm[0 * EXTC + cell], s0 * g);
          unsafeAtomicAdd(&sm[1 * EXTC + cell], s1 * g);
          unsafeAtomicAdd(&sm[2 * EXTC + cell], s2 * g);
          unsafeAtomicAdd(&sm[3 * EXTC + cell], fwv * g);
          unsafeAtomicAdd(&sm[4 * EXTC + cell], g);
        }
      }
    } else {
      // rare outlier: direct global atomics with image-bounds checks
      int base = b * HW;
      for (int dy = 0; dy < 4; ++dy) {
        int iy = iyb + dy - 1;
        if (iy < 0 || iy >= HGT) continue;
        float gy = gyv[dy];
        for (int dx = 0; dx < 4; ++dx) {
          int ix = ixb + dx - 1;
          if (ix < 0 || ix >= WID) continue;
          float g = gxv[dx] * gy;
          int gi = base + iy * WID + ix;
          unsafeAtomicAdd(p + gi, s0 * g);
          unsafeAtomicAdd(p + NPIX + gi, s1 * g);
          unsafeAtomicAdd(p + 2 * NPIX + gi, s2 * g);
          unsafeAtomicAdd(pw + gi, fwv * g);
          unsafeAtomicAdd(rw + gi, g);
        }
      }
    }
  }
  __syncthreads();

  // flush extended tile to global accumulators
  const int base = b * HW;
  for (int c = threadIdx.x; c < EXTC; c += 256) {
    float rv = sm[4 * EXTC + c];
    if (rv == 0.0f) continue;        // untouched cell (every tap adds g > 0.05)
    int cy = c / EXT, cx = c - cy * EXT;
    int gx = ex0 + cx, gy = ey0 + cy;
    if (gx < 0 || gx >= WID || gy < 0 || gy >= HGT) continue;
    int gi = base + gy * WID + gx;
    unsafeAtomicAdd(p + gi,            sm[0 * EXTC + c]);
    unsafeAtomicAdd(p + NPIX + gi,     sm[1 * EXTC + c]);
    unsafeAtomicAdd(p + 2 * NPIX + gi, sm[2 * EXTC + c]);
    unsafeAtomicAdd(pw + gi,           sm[3 * EXTC + c]);
    unsafeAtomicAdd(rw + gi,           rv);
  }
}

// ---------------------------------------------------------------------------
// Kernel 4a: branch-1 accumulate: out = i1*w1 (write), den = w1 (write)
// ---------------------------------------------------------------------------
__global__ __launch_bounds__(256) void acc1_kernel(
    const float* __restrict__ p, const float* __restrict__ pw,
    const float* __restrict__ rw, float* __restrict__ out,
    float* __restrict__ den) {
  int n = blockIdx.x * blockDim.x + threadIdx.x;
  if (n >= NPIX) return;
  int b = n / HW;
  int r = n - b * HW;
  float pwv = pw[n], rwv = rw[n];
  float w = pwv / (rwv + THRESH);
  den[n] = w;
  float scale = w / (pwv + THRESH);
  int ob = b * 3 * HW + r;
  out[ob + 0 * HW] = p[n] * scale;
  out[ob + 1 * HW] = p[NPIX + n] * scale;
  out[ob + 2 * HW] = p[2 * NPIX + n] * scale;
}

// ---------------------------------------------------------------------------
// Kernel 4b: branch-2 accumulate + final blend:
//   out = (out + i2*w2) / (den + w2 + EPS)
// ---------------------------------------------------------------------------
__global__ __launch_bounds__(256) void acc2_kernel(
    const float* __restrict__ p, const float* __restrict__ pw,
    const float* __restrict__ rw, const float* __restrict__ den,
    float* __restrict__ out) {
  int n = blockIdx.x * blockDim.x + threadIdx.x;
  if (n >= NPIX) return;
  int b = n / HW;
  int r = n - b * HW;
  float pwv = pw[n], rwv = rw[n];
  float w = pwv / (rwv + THRESH);
  float scale = w / (pwv + THRESH);
  float d = den[n] + w + EPSV;
  float invd = 1.0f / d;
  int ob = b * 3 * HW + r;
  out[ob + 0 * HW] = (out[ob + 0 * HW] + p[n] * scale) * invd;
  out[ob + 1 * HW] = (out[ob + 1 * HW] + p[NPIX + n] * scale) * invd;
  out[ob + 2 * HW] = (out[ob + 2 * HW] + p[2 * NPIX + n] * scale) * invd;
}

// ---------------------------------------------------------------------------
// Launcher. Workspace layout (floats), 7N total = 103.2 MB:
//   [0, 3N)   p (3 planes); p[0] aliases err scratch (consumed pre-memset)
//   [3N, 4N)  pw   [4N, 5N)  rw   [5N, 6N)  fw   [6N, 7N)  den (w1)
// ---------------------------------------------------------------------------
extern "C" void kernel_launch(void* const* d_in, const int* in_sizes, int n_in,
                              void* d_out, int out_size, void* d_ws,
                              size_t ws_size, hipStream_t stream) {
  const float* input1 = (const float*)d_in[0];
  const float* input2 = (const float*)d_in[1];
  const float* flow3  = (const float*)d_in[2];
  const float* flow4  = (const float*)d_in[3];
  float* out = (float*)d_out;

  float* ws  = (float*)d_ws;
  float* p   = ws;
  float* err = ws;
  float* pw  = ws + (size_t)3 * NPIX;
  float* rw  = ws + (size_t)4 * NPIX;
  float* fw  = ws + (size_t)5 * NPIX;
  float* den = ws + (size_t)6 * NPIX;

  const int threads = 256;
  const int blocks = (NPIX + threads - 1) / threads;
  dim3 sgrid(WID / TILE, (HGT + TILE - 1) / TILE, BATCH);  // 40 x 23 x 4

  // ---- branch 1: warp input2 by flow3, compare to input1, splat input1 ----
  err_kernel<<<blocks, threads, 0, stream>>>(input1, input2, flow3, err);
  fw_kernel<<<blocks, threads, 0, stream>>>(err, fw);
  hipMemsetAsync(ws, 0, (size_t)5 * NPIX * sizeof(float), stream);  // p,pw,rw
  splat_tiled_kernel<<<sgrid, threads, 0, stream>>>(flow3, input1, fw, p, pw, rw);
  acc1_kernel<<<blocks, threads, 0, stream>>>(p, pw, rw, out, den);

  // ---- branch 2: warp input1 by flow4, compare to input2, splat input2 ----
  err_kernel<<<blocks, threads, 0, stream>>>(input2, input1, flow4, err);
  fw_kernel<<<blocks, threads, 0, stream>>>(err, fw);
  hipMemsetAsync(ws, 0, (size_t)5 * NPIX * sizeof(float), stream);
  splat_tiled_kernel<<<sgrid, threads, 0, stream>>>(flow4, input2, fw, p, pw, rw);
  acc2_kernel<<<blocks, threads, 0, stream>>>(p, pw, rw, den, out);
}